// Round 6
// baseline (211.847 us; speedup 1.0000x reference)
//
#include <hip/hip_runtime.h>
#include <math.h>

#define KHALF 5
#define MAXF 256  // max fire count per batch (Lp1 <= 128 for this problem)

// K1: effective conv->proj weights: w_eff[k*D+d] = sum_c conv_w[k,d,c]*proj_w[c]
// One WAVE per output element; extra wave computes b_eff.
__global__ void k_weff(const float* __restrict__ conv_w, const float* __restrict__ conv_b,
                       const float* __restrict__ proj_w, const float* __restrict__ proj_b,
                       float* __restrict__ w_eff, float* __restrict__ b_eff,
                       int KD, int C) {
    int gid = blockIdx.x * blockDim.x + threadIdx.x;
    int wave = gid >> 6;
    int lane = gid & 63;
    if (wave > KD) return;
    float s = 0.f;
    if (wave < KD) {
        const float* row = conv_w + (size_t)wave * C;
        for (int c = lane * 4; c < C; c += 256) {
            float4 v = *reinterpret_cast<const float4*>(row + c);
            float4 w = *reinterpret_cast<const float4*>(proj_w + c);
            s += v.x * w.x + v.y * w.y + v.z * w.z + v.w * w.w;
        }
    } else {
        for (int c = lane; c < C; c += 64) s += conv_b[c] * proj_w[c];
    }
#pragma unroll
    for (int off = 32; off > 0; off >>= 1) s += __shfl_down(s, off, 64);
    if (lane == 0) {
        if (wave < KD) w_eff[wave] = s;
        else           b_eff[0] = s + proj_b[0];
    }
}

// K2a v2: q[u][k] = dot(eouts[u,:], w_eff[k,:]), k=0..10. D==512 specialized.
// Block = 256 threads handles 64 rows; wave s owns d-split [s*32, s*32+32) of
// each 128-d chunk. eouts staged coalesced->LDS (stride 132: 2-way bank
// aliasing for b128, free). Each thread: 11 VGPR accumulators, row = lane.
// w_eff index is wave-uniform (readfirstlane) -> scalar loads (SGPR operand).
// NO cross-lane reduction at all; 4-way split reduced through LDS at the end.
__global__ __launch_bounds__(256) void k_qdot(const float* __restrict__ eouts,
                                              const float* __restrict__ w_eff,
                                              float* __restrict__ q, int BT) {
    __shared__ float tile[64 * 132];
    __shared__ float part[64 * 48];
    const int u0 = blockIdx.x * 64;
    const int lane = threadIdx.x & 63;
    const int s = __builtin_amdgcn_readfirstlane(threadIdx.x >> 6);  // 0..3, SGPR
    float acc[11];
#pragma unroll
    for (int k = 0; k < 11; ++k) acc[k] = 0.f;
    for (int c = 0; c < 4; ++c) {
        __syncthreads();
#pragma unroll
        for (int it = 0; it < 8; ++it) {
            int idx = it * 256 + threadIdx.x;
            int r = idx >> 5, j4 = idx & 31;
            float4 v = *reinterpret_cast<const float4*>(
                eouts + (size_t)(u0 + r) * 512 + c * 128 + j4 * 4);
            *reinterpret_cast<float4*>(&tile[r * 132 + j4 * 4]) = v;
        }
        __syncthreads();
#pragma unroll
        for (int j4 = 0; j4 < 8; ++j4) {
            float4 av = *reinterpret_cast<const float4*>(&tile[lane * 132 + s * 32 + j4 * 4]);
            int dg = c * 128 + s * 32 + j4 * 4;
#pragma unroll
            for (int k = 0; k < 11; ++k) {
                float4 wv = *reinterpret_cast<const float4*>(w_eff + k * 512 + dg);
                acc[k] += av.x * wv.x + av.y * wv.y + av.z * wv.z + av.w * wv.w;
            }
        }
    }
#pragma unroll
    for (int k = 0; k < 11; ++k) part[lane * 48 + s * 12 + k] = acc[k];
    __syncthreads();
    if (threadIdx.x < 64) {
        int r = threadIdx.x;
        const float* p = &part[r * 48];
        float o[12];
#pragma unroll
        for (int k = 0; k < 11; ++k)
            o[k] = (p[k] + p[12 + k]) + (p[24 + k] + p[36 + k]);
        o[11] = 0.f;
        float4* dst = reinterpret_cast<float4*>(q + (size_t)(u0 + r) * 12);
        dst[0] = make_float4(o[0], o[1], o[2], o[3]);
        dst[1] = make_float4(o[4], o[5], o[6], o[7]);
        dst[2] = make_float4(o[8], o[9], o[10], o[11]);
    }
}

// K2 fallback (generic D): windowed dot, one wave per (b,t), writes alpha.
__global__ void k_alpha(const float* __restrict__ eouts,
                        const float* __restrict__ w_eff,
                        const float* __restrict__ b_eff,
                        float* __restrict__ alpha,
                        int B, int T, int D) {
    const int W = 2 * KHALF + 1;
    int gid = blockIdx.x * blockDim.x + threadIdx.x;
    int wave = gid >> 6;
    int lane = gid & 63;
    if (wave >= B * T) return;
    int b = wave / T;
    int t = wave - b * T;
    int WD = W * D;
    int t0 = t - KHALF;
    float s = 0.f;
    if (t0 >= 0 && t0 + W <= T) {
        const float* base = eouts + ((size_t)b * T + t0) * D;
        for (int j = lane * 4; j < WD; j += 256) {
            float4 v = *reinterpret_cast<const float4*>(base + j);
            float4 w = *reinterpret_cast<const float4*>(w_eff + j);
            s += v.x * w.x + v.y * w.y + v.z * w.z + v.w * w.w;
        }
    } else {
        const float* base = eouts + (size_t)b * T * D;
        for (int j = lane; j < WD; j += 64) {
            int tt = t0 + j / D;
            if (tt >= 0 && tt < T) {
                int d = j - (j / D) * D;
                s += base[(size_t)tt * D + d] * w_eff[j];
            }
        }
    }
#pragma unroll
    for (int off = 32; off > 0; off >>= 1) s += __shfl_down(s, off, 64);
    if (lane == 0) {
        float logit = s + b_eff[0];
        alpha[(size_t)b * T + t] = 1.f / (1.f + expf(-logit));
    }
}

// K3: sigma + rowsum + normalize + fire scan, one block per batch.
// use_q: alpha computed in-kernel from q diagonals; else read alpha_in.
__global__ void k_chain(const float* __restrict__ q,
                        const float* __restrict__ alpha_in,
                        int use_q,
                        const float* __restrict__ b_eff,
                        const int* __restrict__ elens,
                        const int* __restrict__ ylens,
                        float* __restrict__ alpha,
                        float* __restrict__ alpha_sum,
                        int* __restrict__ n_fired,
                        int* __restrict__ fire_t,
                        float* __restrict__ fire_a1,
                        float* __restrict__ fire_a2,
                        int T, int Lp1) {
    extern __shared__ float an[];
    __shared__ float sm[16];
    __shared__ float stot;
    int b = blockIdx.x;
    if (use_q) {
        const float* qb = q + (size_t)b * T * 12;
        float bias = b_eff[0];
        for (int t = threadIdx.x; t < T; t += blockDim.x) {
            float sacc = bias;
            int tw = t - KHALF;
#pragma unroll
            for (int k = 0; k < 11; ++k) {
                int u = tw + k;
                if (u >= 0 && u < T) sacc += qb[(size_t)u * 12 + k];
            }
            float al = 1.f / (1.f + expf(-sacc));
            alpha[(size_t)b * T + t] = al;
            an[t] = al;
        }
    } else {
        for (int t = threadIdx.x; t < T; t += blockDim.x)
            an[t] = alpha_in[(size_t)b * T + t];
    }
    __syncthreads();
    // --- row sum (same order as prior rounds) ---
    float s = 0.f;
    for (int i = threadIdx.x; i < T; i += blockDim.x) s += an[i];
    int lane = threadIdx.x & 63;
    int w = threadIdx.x >> 6;
#pragma unroll
    for (int off = 32; off > 0; off >>= 1) s += __shfl_down(s, off, 64);
    if (lane == 0) sm[w] = s;
    __syncthreads();
    if (threadIdx.x == 0) {
        float tot = 0.f;
        int nw = blockDim.x >> 6;
        for (int i = 0; i < nw; ++i) tot += sm[i];
        stot = tot;
        alpha_sum[b] = tot;
    }
    __syncthreads();
    float ssum = stot;
    float yl = (float)ylens[b];
    for (int i = threadIdx.x; i < T; i += blockDim.x) an[i] = an[i] / ssum * yl;
    __syncthreads();
    if (threadIdx.x >= 64) return;  // wave 0 only

    int elen = elens[b];
    if (elen > T) elen = T;
    const int ylen = ylens[b];
    int* __restrict__ ft = fire_t + (size_t)b * Lp1;
    float* __restrict__ fa1 = fire_a1 + (size_t)b * Lp1;
    float* __restrict__ fa2 = fire_a2 + (size_t)b * Lp1;

    float accum = 0.f;
    int n = 0;
    bool done = false;
    for (int t0 = 0; t0 < elen && !done; t0 += 64) {
        int nv = elen - t0;
        if (nv > 64) nv = 64;
        float a = (lane < nv) ? an[t0 + lane] : 0.f;
        float P = a;
#pragma unroll
        for (int off = 1; off < 64; off <<= 1) {
            float tmp = __shfl_up(P, off, 64);
            if (lane >= off) P += tmp;
        }
        unsigned long long validmask =
            (nv == 64) ? ~0ull : ((1ull << nv) - 1ull);
        float base = accum;
        int start = 0;
        while (true) {
            bool cond = (base + P >= 0.9f);
            unsigned long long bal = __ballot(cond) & validmask;
            if (start > 0) bal &= (~0ull) << start;
            if (bal == 0) break;
            int u = __builtin_ctzll(bal);
            float Pu = __shfl(P, u, 64);
            float au = __shfl(a, u, 64);
            float accum_f = base + Pu;
            float ak1 = 1.f - accum_f;
            float ak2 = au - ak1;
            if (lane == 0) {
                ft[n] = t0 + u;
                fa1[n] = ak1;
                fa2[n] = ak2;
            }
            ++n;
            if (n >= ylen) { done = true; break; }
            base = ak2 - Pu;
            start = u + 1;
            if (start >= nv) break;
        }
        if (!done) {
            float Plast = __shfl(P, nv - 1, 64);
            accum = base + Plast;
        }
    }
    if (lane == 0) n_fired[b] = n;
}

// K4: fused aws writer (incl. background zeros — replaces memset) + fired
// (incl. zero rows >= n_fired). Weight recompute fl(fl(alpha/s)*yl) is
// div-then-mul, bit-identical to k_chain's normalize.
__global__ void k_awfired(const float* __restrict__ eouts,
                          const float* __restrict__ alpha,
                          const float* __restrict__ alpha_sum,
                          const int* __restrict__ elens,
                          const int* __restrict__ ylens,
                          const int* __restrict__ n_fired,
                          const int* __restrict__ fire_t,
                          const float* __restrict__ fire_a1,
                          const float* __restrict__ fire_a2,
                          float* __restrict__ aws,
                          float* __restrict__ fired,
                          int T, int D, int L, int Lp1,
                          int AB, int tcpb, int DB) {
    if ((int)blockIdx.x < AB) {
        // ---- aws writer role: block = (b, 256-wide t-chunk), loops all Lp1 rows
        __shared__ int fts[MAXF];
        __shared__ float a1s[MAXF];
        __shared__ float a2s[MAXF];
        int b = blockIdx.x / tcpb;
        int tc = blockIdx.x % tcpb;
        int nf = n_fired[b];
        for (int i = threadIdx.x; i < nf; i += blockDim.x) {
            fts[i] = fire_t[(size_t)b * Lp1 + i];
            a1s[i] = fire_a1[(size_t)b * Lp1 + i];
            a2s[i] = fire_a2[(size_t)b * Lp1 + i];
        }
        __syncthreads();
        int t = tc * 256 + threadIdx.x;
        if (t >= T) return;
        int elen = elens[b];
        if (elen > T) elen = T;
        int ylen = ylens[b];
        bool active = (t < elen);
        int rowi = 0;
        bool isfire = false;
        float v1 = 0.f, v2 = 0.f;
        if (active) {
            int lo = 0, hi = nf;
            while (lo < hi) {
                int mid = (lo + hi) >> 1;
                if (fts[mid] < t) lo = mid + 1; else hi = mid;
            }
            rowi = lo;
            isfire = (rowi < nf && fts[rowi] == t);
            if (isfire) { v1 = a1s[rowi]; v2 = a2s[rowi]; }
            else if (rowi < ylen) v1 = alpha[(size_t)b * T + t] / alpha_sum[b] * (float)ylen;
            else active = false;
        }
        float* col = aws + (size_t)b * Lp1 * T + t;
        for (int r = 0; r < Lp1; ++r) {
            float v = 0.f;
            if (active) {
                if (r == rowi) v = v1;
                else if (isfire && r == rowi + 1) v = v2;
            }
            col[(size_t)r * T] = v;  // coalesced across threads (consecutive t)
        }
    } else {
        // ---- fired role: block = (b, n, d-chunk)
        int idx = blockIdx.x - AB;
        int b = idx / (L * DB);
        int rem = idx % (L * DB);
        int n = rem / DB;
        int d = (rem % DB) * 256 + threadIdx.x;
        if (d >= D) return;
        int nf = n_fired[b];
        float* dst = fired + ((size_t)b * L + n) * D + d;
        if (n >= nf) { *dst = 0.f; return; }
        int t0 = (n == 0) ? 0 : fire_t[(size_t)b * Lp1 + n - 1];
        int t1 = fire_t[(size_t)b * Lp1 + n];
        float ak1 = fire_a1[(size_t)b * Lp1 + n];
        float ak2p = (n > 0) ? fire_a2[(size_t)b * Lp1 + n - 1] : 0.f;
        float ssum = alpha_sum[b];
        float yl = (float)ylens[b];
        const float* e = eouts + ((size_t)b * T + t0) * D + d;
        float accv = 0.f;
        for (int t = t0; t <= t1; ++t, e += D) {
            float wgt;
            if (t == t1) wgt = ak1;                 // fire step (covers t0==t1, n==0)
            else if (t == t0 && n > 0) wgt = ak2p;  // carry-in from previous fire
            else wgt = alpha[(size_t)b * T + t] / ssum * yl;
            accv += wgt * e[0];
        }
        *dst = accv;
    }
}

extern "C" void kernel_launch(void* const* d_in, const int* in_sizes, int n_in,
                              void* d_out, int out_size, void* d_ws, size_t ws_size,
                              hipStream_t stream) {
    const float* eouts  = (const float*)d_in[0];
    const float* conv_w = (const float*)d_in[1];
    const float* conv_b = (const float*)d_in[2];
    const float* proj_w = (const float*)d_in[3];
    const float* proj_b = (const float*)d_in[4];
    const int*   elens  = (const int*)d_in[5];
    const int*   ylens  = (const int*)d_in[6];

    const int B = in_sizes[5];
    const int C = in_sizes[2];
    const int W = 2 * KHALF + 1;
    const int D = in_sizes[1] / (W * C);
    const int T = in_sizes[0] / (B * D);
    const int L = (out_size - 2 * B * T) / (B * (D + T));
    const int Lp1 = L + 1;
    const int BT = B * T;

    float* out   = (float*)d_out;
    float* fired = out;                      // [B, L, D]
    float* alpha = out + (size_t)B * L * D;  // [B, T]
    float* aws   = alpha + (size_t)B * T;    // [B, 1, Lp1, T]

    // workspace layout (all written before read within this launch)
    char*  ws        = (char*)d_ws;
    float* w_eff     = (float*)ws;                              // W*D floats
    float* b_eff     = (float*)(ws + (size_t)W * D * 4);        // 1 float (+pad)
    float* alpha_sum = b_eff + 16;                              // B floats
    int*   n_fired   = (int*)(alpha_sum + B + 16);              // B ints
    int*   fire_t    = n_fired + B + 16;                        // B*Lp1 ints
    float* fire_a1   = (float*)(fire_t + (size_t)B * Lp1 + 16); // B*Lp1 floats
    float* fire_a2   = fire_a1 + (size_t)B * Lp1 + 16;          // B*Lp1 floats
    float* qbuf      = fire_a2 + (size_t)B * Lp1 + 16;          // BT*12 floats
    size_t ws_need   = (size_t)((char*)(qbuf + (size_t)BT * 12) - ws);

    const int KD = W * D;
    {
        long long threads = (long long)(KD + 1) * 64;
        int blocks = (int)((threads + 255) / 256);
        k_weff<<<blocks, 256, 0, stream>>>(conv_w, conv_b, proj_w, proj_b,
                                           w_eff, b_eff, KD, C);
    }

    const bool fast = (ws_size >= ws_need) && (D == 512) && (BT % 64 == 0);
    if (fast) {
        k_qdot<<<BT / 64, 256, 0, stream>>>(eouts, w_eff, qbuf, BT);
    } else {
        long long threads = (long long)BT * 64;
        int blocks = (int)((threads + 255) / 256);
        k_alpha<<<blocks, 256, 0, stream>>>(eouts, w_eff, b_eff, alpha, B, T, D);
    }

    k_chain<<<B, 256, T * sizeof(float), stream>>>(
        fast ? qbuf : (const float*)nullptr, alpha, fast ? 1 : 0,
        b_eff, elens, ylens, alpha, alpha_sum,
        n_fired, fire_t, fire_a1, fire_a2, T, Lp1);

    {
        int tcpb = (T + 255) / 256;
        int AB = B * tcpb;
        int DB = (D + 255) / 256;
        int FB = B * L * DB;
        k_awfired<<<AB + FB, 256, 0, stream>>>(eouts, alpha, alpha_sum,
                                               elens, ylens, n_fired,
                                               fire_t, fire_a1, fire_a2,
                                               aws, fired, T, D, L, Lp1,
                                               AB, tcpb, DB);
    }
}

// Round 7
// 196.699 us; speedup vs baseline: 1.0770x; 1.0770x over previous
//
#include <hip/hip_runtime.h>
#include <math.h>

#define KHALF 5
#define MAXF 256  // max fire count per batch (Lp1 <= 128 for this problem)

// K1: effective conv->proj weights: w_eff[k*D+d] = sum_c conv_w[k,d,c]*proj_w[c]
// One WAVE per output element; extra wave computes b_eff.
__global__ void k_weff(const float* __restrict__ conv_w, const float* __restrict__ conv_b,
                       const float* __restrict__ proj_w, const float* __restrict__ proj_b,
                       float* __restrict__ w_eff, float* __restrict__ b_eff,
                       int KD, int C) {
    int gid = blockIdx.x * blockDim.x + threadIdx.x;
    int wave = gid >> 6;
    int lane = gid & 63;
    if (wave > KD) return;
    float s = 0.f;
    if (wave < KD) {
        const float* row = conv_w + (size_t)wave * C;
        for (int c = lane * 4; c < C; c += 256) {
            float4 v = *reinterpret_cast<const float4*>(row + c);
            float4 w = *reinterpret_cast<const float4*>(proj_w + c);
            s += v.x * w.x + v.y * w.y + v.z * w.z + v.w * w.w;
        }
    } else {
        for (int c = lane; c < C; c += 64) s += conv_b[c] * proj_w[c];
    }
#pragma unroll
    for (int off = 32; off > 0; off >>= 1) s += __shfl_down(s, off, 64);
    if (lane == 0) {
        if (wave < KD) w_eff[wave] = s;
        else           b_eff[0] = s + proj_b[0];
    }
}

// K2a: q[u][k] = dot(eouts[u,:], w_eff[k,:]), k=0..10. D==512 specialized.
// part stride 49 (odd): 48 gave banks {0,16} only -> 32-way conflict on the
// partial-store phase; 49 spreads all 32 banks.
__global__ __launch_bounds__(256) void k_qdot(const float* __restrict__ eouts,
                                              const float* __restrict__ w_eff,
                                              float* __restrict__ q, int BT) {
    __shared__ float tile[64 * 132];
    __shared__ float part[64 * 49];
    const int u0 = blockIdx.x * 64;
    const int lane = threadIdx.x & 63;
    const int s = __builtin_amdgcn_readfirstlane(threadIdx.x >> 6);  // 0..3, SGPR
    float acc[11];
#pragma unroll
    for (int k = 0; k < 11; ++k) acc[k] = 0.f;
    for (int c = 0; c < 4; ++c) {
        __syncthreads();
#pragma unroll
        for (int it = 0; it < 8; ++it) {
            int idx = it * 256 + threadIdx.x;
            int r = idx >> 5, j4 = idx & 31;
            float4 v = *reinterpret_cast<const float4*>(
                eouts + (size_t)(u0 + r) * 512 + c * 128 + j4 * 4);
            *reinterpret_cast<float4*>(&tile[r * 132 + j4 * 4]) = v;
        }
        __syncthreads();
#pragma unroll
        for (int j4 = 0; j4 < 8; ++j4) {
            float4 av = *reinterpret_cast<const float4*>(&tile[lane * 132 + s * 32 + j4 * 4]);
            int dg = c * 128 + s * 32 + j4 * 4;
#pragma unroll
            for (int k = 0; k < 11; ++k) {
                float4 wv = *reinterpret_cast<const float4*>(w_eff + k * 512 + dg);
                acc[k] += av.x * wv.x + av.y * wv.y + av.z * wv.z + av.w * wv.w;
            }
        }
    }
#pragma unroll
    for (int k = 0; k < 11; ++k) part[lane * 49 + s * 12 + k] = acc[k];
    __syncthreads();
    if (threadIdx.x < 64) {
        int r = threadIdx.x;
        const float* p = &part[r * 49];
        float o[12];
#pragma unroll
        for (int k = 0; k < 11; ++k)
            o[k] = (p[k] + p[12 + k]) + (p[24 + k] + p[36 + k]);
        o[11] = 0.f;
        float4* dst = reinterpret_cast<float4*>(q + (size_t)(u0 + r) * 12);
        dst[0] = make_float4(o[0], o[1], o[2], o[3]);
        dst[1] = make_float4(o[4], o[5], o[6], o[7]);
        dst[2] = make_float4(o[8], o[9], o[10], o[11]);
    }
}

// K2b: alpha[b,t] = sigmoid(sum_k q[t-5+k][k] + bias), plus deterministic
// per-block (256-t) partial sums of alpha for the normalization.
// q slab [t0-5, t0+261) staged contiguously (validity is row-aligned: gi<0 or
// gi>=T*12 exactly for out-of-range rows -> zero-pad, added as exact +0).
__global__ __launch_bounds__(256) void k_sigpart(const float* __restrict__ q,
                                                 const float* __restrict__ b_eff,
                                                 float* __restrict__ alpha,
                                                 float* __restrict__ partials,
                                                 int T, int tcb) {
    __shared__ float qs[266 * 12];
    __shared__ float psm[4];
    int bx = blockIdx.x;
    int b = bx / tcb, tc = bx % tcb;
    int t0 = tc * 256;
    const float* qb = q + (size_t)b * T * 12;
    const int base = (t0 - 5) * 12;
    const int lim = T * 12;
    for (int i = threadIdx.x; i < 266 * 12; i += 256) {
        int gi = base + i;
        qs[i] = (gi >= 0 && gi < lim) ? qb[gi] : 0.f;
    }
    __syncthreads();
    int t = t0 + threadIdx.x;
    float sacc = b_eff[0];
#pragma unroll
    for (int k = 0; k < 11; ++k) sacc += qs[(threadIdx.x + k) * 12 + k];
    float al = 1.f / (1.f + expf(-sacc));
    alpha[(size_t)b * T + t] = al;
    // deterministic block sum
    float s = al;
    int lane = threadIdx.x & 63;
    int w = threadIdx.x >> 6;
#pragma unroll
    for (int off = 32; off > 0; off >>= 1) s += __shfl_down(s, off, 64);
    if (lane == 0) psm[w] = s;
    __syncthreads();
    if (threadIdx.x == 0) {
        float tot = 0.f;
        for (int i = 0; i < 4; ++i) tot += psm[i];
        partials[bx] = tot;
    }
}

// K2 fallback (generic D): windowed dot, one wave per (b,t), writes alpha.
__global__ void k_alpha(const float* __restrict__ eouts,
                        const float* __restrict__ w_eff,
                        const float* __restrict__ b_eff,
                        float* __restrict__ alpha,
                        int B, int T, int D) {
    const int W = 2 * KHALF + 1;
    int gid = blockIdx.x * blockDim.x + threadIdx.x;
    int wave = gid >> 6;
    int lane = gid & 63;
    if (wave >= B * T) return;
    int b = wave / T;
    int t = wave - b * T;
    int WD = W * D;
    int t0 = t - KHALF;
    float s = 0.f;
    if (t0 >= 0 && t0 + W <= T) {
        const float* base = eouts + ((size_t)b * T + t0) * D;
        for (int j = lane * 4; j < WD; j += 256) {
            float4 v = *reinterpret_cast<const float4*>(base + j);
            float4 w = *reinterpret_cast<const float4*>(w_eff + j);
            s += v.x * w.x + v.y * w.y + v.z * w.z + v.w * w.w;
        }
    } else {
        const float* base = eouts + (size_t)b * T * D;
        for (int j = lane; j < WD; j += 64) {
            int tt = t0 + j / D;
            if (tt >= 0 && tt < T) {
                int d = j - (j / D) * D;
                s += base[(size_t)tt * D + d] * w_eff[j];
            }
        }
    }
#pragma unroll
    for (int off = 32; off > 0; off >>= 1) s += __shfl_down(s, off, 64);
    if (lane == 0) {
        float logit = s + b_eff[0];
        alpha[(size_t)b * T + t] = 1.f / (1.f + expf(-logit));
    }
}

// K3: rowsum (from partials in fast path) + normalize + fire scan.
// One block per batch; scan on wave 0 (unchanged ballot/prefix structure).
__global__ void k_chain(const float* __restrict__ alpha_in,
                        int use_part,
                        const float* __restrict__ partials, int npart,
                        const int* __restrict__ elens,
                        const int* __restrict__ ylens,
                        float* __restrict__ alpha_sum,
                        int* __restrict__ n_fired,
                        int* __restrict__ fire_t,
                        float* __restrict__ fire_a1,
                        float* __restrict__ fire_a2,
                        int T, int Lp1) {
    extern __shared__ float an[];
    __shared__ float sm[16];
    __shared__ float stot;
    int b = blockIdx.x;
    const float* row = alpha_in + (size_t)b * T;
    for (int i = threadIdx.x; i < T; i += blockDim.x) an[i] = row[i];
    __syncthreads();
    if (use_part) {
        if (threadIdx.x == 0) {
            float tot = 0.f;
            for (int i = 0; i < npart; ++i) tot += partials[b * npart + i];
            stot = tot;
            alpha_sum[b] = tot;
        }
    } else {
        float s = 0.f;
        for (int i = threadIdx.x; i < T; i += blockDim.x) s += an[i];
        int lane0 = threadIdx.x & 63;
        int w0 = threadIdx.x >> 6;
#pragma unroll
        for (int off = 32; off > 0; off >>= 1) s += __shfl_down(s, off, 64);
        if (lane0 == 0) sm[w0] = s;
        __syncthreads();
        if (threadIdx.x == 0) {
            float tot = 0.f;
            int nw = blockDim.x >> 6;
            for (int i = 0; i < nw; ++i) tot += sm[i];
            stot = tot;
            alpha_sum[b] = tot;
        }
    }
    __syncthreads();
    float ssum = stot;
    float yl = (float)ylens[b];
    for (int i = threadIdx.x; i < T; i += blockDim.x) an[i] = an[i] / ssum * yl;
    __syncthreads();
    if (threadIdx.x >= 64) return;  // wave 0 only
    int lane = threadIdx.x;

    int elen = elens[b];
    if (elen > T) elen = T;
    const int ylen = ylens[b];
    int* __restrict__ ft = fire_t + (size_t)b * Lp1;
    float* __restrict__ fa1 = fire_a1 + (size_t)b * Lp1;
    float* __restrict__ fa2 = fire_a2 + (size_t)b * Lp1;

    float accum = 0.f;
    int n = 0;
    bool done = false;
    for (int t0 = 0; t0 < elen && !done; t0 += 64) {
        int nv = elen - t0;
        if (nv > 64) nv = 64;
        float a = (lane < nv) ? an[t0 + lane] : 0.f;
        float P = a;
#pragma unroll
        for (int off = 1; off < 64; off <<= 1) {
            float tmp = __shfl_up(P, off, 64);
            if (lane >= off) P += tmp;
        }
        unsigned long long validmask =
            (nv == 64) ? ~0ull : ((1ull << nv) - 1ull);
        float base = accum;
        int start = 0;
        while (true) {
            bool cond = (base + P >= 0.9f);
            unsigned long long bal = __ballot(cond) & validmask;
            if (start > 0) bal &= (~0ull) << start;
            if (bal == 0) break;
            int u = __builtin_ctzll(bal);
            float Pu = __shfl(P, u, 64);
            float au = __shfl(a, u, 64);
            float accum_f = base + Pu;
            float ak1 = 1.f - accum_f;
            float ak2 = au - ak1;
            if (lane == 0) {
                ft[n] = t0 + u;
                fa1[n] = ak1;
                fa2[n] = ak2;
            }
            ++n;
            if (n >= ylen) { done = true; break; }
            base = ak2 - Pu;
            start = u + 1;
            if (start >= nv) break;
        }
        if (!done) {
            float Plast = __shfl(P, nv - 1, 64);
            accum = base + Plast;
        }
    }
    if (lane == 0) n_fired[b] = n;
}

// K4: fused aws writer (incl. background zeros) + fired (incl. zero tail rows).
__global__ void k_awfired(const float* __restrict__ eouts,
                          const float* __restrict__ alpha,
                          const float* __restrict__ alpha_sum,
                          const int* __restrict__ elens,
                          const int* __restrict__ ylens,
                          const int* __restrict__ n_fired,
                          const int* __restrict__ fire_t,
                          const float* __restrict__ fire_a1,
                          const float* __restrict__ fire_a2,
                          float* __restrict__ aws,
                          float* __restrict__ fired,
                          int T, int D, int L, int Lp1,
                          int AB, int tcpb, int DB) {
    if ((int)blockIdx.x < AB) {
        __shared__ int fts[MAXF];
        __shared__ float a1s[MAXF];
        __shared__ float a2s[MAXF];
        int b = blockIdx.x / tcpb;
        int tc = blockIdx.x % tcpb;
        int nf = n_fired[b];
        for (int i = threadIdx.x; i < nf; i += blockDim.x) {
            fts[i] = fire_t[(size_t)b * Lp1 + i];
            a1s[i] = fire_a1[(size_t)b * Lp1 + i];
            a2s[i] = fire_a2[(size_t)b * Lp1 + i];
        }
        __syncthreads();
        int t = tc * 256 + threadIdx.x;
        if (t >= T) return;
        int elen = elens[b];
        if (elen > T) elen = T;
        int ylen = ylens[b];
        bool active = (t < elen);
        int rowi = 0;
        bool isfire = false;
        float v1 = 0.f, v2 = 0.f;
        if (active) {
            int lo = 0, hi = nf;
            while (lo < hi) {
                int mid = (lo + hi) >> 1;
                if (fts[mid] < t) lo = mid + 1; else hi = mid;
            }
            rowi = lo;
            isfire = (rowi < nf && fts[rowi] == t);
            if (isfire) { v1 = a1s[rowi]; v2 = a2s[rowi]; }
            else if (rowi < ylen) v1 = alpha[(size_t)b * T + t] / alpha_sum[b] * (float)ylen;
            else active = false;
        }
        float* col = aws + (size_t)b * Lp1 * T + t;
        for (int r = 0; r < Lp1; ++r) {
            float v = 0.f;
            if (active) {
                if (r == rowi) v = v1;
                else if (isfire && r == rowi + 1) v = v2;
            }
            col[(size_t)r * T] = v;
        }
    } else {
        int idx = blockIdx.x - AB;
        int b = idx / (L * DB);
        int rem = idx % (L * DB);
        int n = rem / DB;
        int d = (rem % DB) * 256 + threadIdx.x;
        if (d >= D) return;
        int nf = n_fired[b];
        float* dst = fired + ((size_t)b * L + n) * D + d;
        if (n >= nf) { *dst = 0.f; return; }
        int t0 = (n == 0) ? 0 : fire_t[(size_t)b * Lp1 + n - 1];
        int t1 = fire_t[(size_t)b * Lp1 + n];
        float ak1 = fire_a1[(size_t)b * Lp1 + n];
        float ak2p = (n > 0) ? fire_a2[(size_t)b * Lp1 + n - 1] : 0.f;
        float ssum = alpha_sum[b];
        float yl = (float)ylens[b];
        const float* e = eouts + ((size_t)b * T + t0) * D + d;
        float accv = 0.f;
        for (int t = t0; t <= t1; ++t, e += D) {
            float wgt;
            if (t == t1) wgt = ak1;
            else if (t == t0 && n > 0) wgt = ak2p;
            else wgt = alpha[(size_t)b * T + t] / ssum * yl;
            accv += wgt * e[0];
        }
        *dst = accv;
    }
}

extern "C" void kernel_launch(void* const* d_in, const int* in_sizes, int n_in,
                              void* d_out, int out_size, void* d_ws, size_t ws_size,
                              hipStream_t stream) {
    const float* eouts  = (const float*)d_in[0];
    const float* conv_w = (const float*)d_in[1];
    const float* conv_b = (const float*)d_in[2];
    const float* proj_w = (const float*)d_in[3];
    const float* proj_b = (const float*)d_in[4];
    const int*   elens  = (const int*)d_in[5];
    const int*   ylens  = (const int*)d_in[6];

    const int B = in_sizes[5];
    const int C = in_sizes[2];
    const int W = 2 * KHALF + 1;
    const int D = in_sizes[1] / (W * C);
    const int T = in_sizes[0] / (B * D);
    const int L = (out_size - 2 * B * T) / (B * (D + T));
    const int Lp1 = L + 1;
    const int BT = B * T;
    const int tcb = T / 256;

    float* out   = (float*)d_out;
    float* fired = out;                      // [B, L, D]
    float* alpha = out + (size_t)B * L * D;  // [B, T]
    float* aws   = alpha + (size_t)B * T;    // [B, 1, Lp1, T]

    char*  ws        = (char*)d_ws;
    float* w_eff     = (float*)ws;                              // W*D floats
    float* b_eff     = (float*)(ws + (size_t)W * D * 4);        // 1 float (+pad)
    float* alpha_sum = b_eff + 16;                              // B floats
    int*   n_fired   = (int*)(alpha_sum + B + 16);              // B ints
    int*   fire_t    = n_fired + B + 16;                        // B*Lp1 ints
    float* fire_a1   = (float*)(fire_t + (size_t)B * Lp1 + 16); // B*Lp1 floats
    float* fire_a2   = fire_a1 + (size_t)B * Lp1 + 16;          // B*Lp1 floats
    float* qbuf      = fire_a2 + (size_t)B * Lp1 + 16;          // BT*12 floats
    float* partials  = qbuf + (size_t)BT * 12 + 16;             // B*tcb floats
    size_t ws_need   = (size_t)((char*)(partials + (size_t)B * tcb + 16) - ws);

    const int KD = W * D;
    {
        long long threads = (long long)(KD + 1) * 64;
        int blocks = (int)((threads + 255) / 256);
        k_weff<<<blocks, 256, 0, stream>>>(conv_w, conv_b, proj_w, proj_b,
                                           w_eff, b_eff, KD, C);
    }

    const bool fast = (ws_size >= ws_need) && (D == 512) &&
                      (BT % 64 == 0) && (T % 256 == 0);
    if (fast) {
        k_qdot<<<BT / 64, 256, 0, stream>>>(eouts, w_eff, qbuf, BT);
        k_sigpart<<<B * tcb, 256, 0, stream>>>(qbuf, b_eff, alpha, partials, T, tcb);
    } else {
        long long threads = (long long)BT * 64;
        int blocks = (int)((threads + 255) / 256);
        k_alpha<<<blocks, 256, 0, stream>>>(eouts, w_eff, b_eff, alpha, B, T, D);
    }

    k_chain<<<B, 256, T * sizeof(float), stream>>>(
        alpha, fast ? 1 : 0, partials, tcb,
        elens, ylens, alpha_sum,
        n_fired, fire_t, fire_a1, fire_a2, T, Lp1);

    {
        int tcpb = (T + 255) / 256;
        int AB = B * tcpb;
        int DB = (D + 255) / 256;
        int FB = B * L * DB;
        k_awfired<<<AB + FB, 256, 0, stream>>>(eouts, alpha, alpha_sum,
                                               elens, ylens, n_fired,
                                               fire_t, fire_a1, fire_a2,
                                               aws, fired, T, D, L, Lp1,
                                               AB, tcpb, DB);
    }
}